// Round 1
// baseline (805.731 us; speedup 1.0000x reference)
//
#include <hip/hip_runtime.h>
#include <stdint.h>

#define NB   16
#define NS   2048
#define ND   1024
#define NH   512
#define SCALE 0.044194173824159216f  // 1/sqrt(512)

typedef __attribute__((ext_vector_type(4))) float f32x4;
typedef __attribute__((ext_vector_type(8))) short s16x8;

__device__ __forceinline__ short f2bf(float f) {
  __bf16 h = (__bf16)f;
  return __builtin_bit_cast(short, h);
}

__device__ __forceinline__ void gl_lds16(const void* g, void* l) {
  __builtin_amdgcn_global_load_lds(
      (const __attribute__((address_space(1))) void*)g,
      (__attribute__((address_space(3))) void*)l, 16, 0, 0);
}

#define MFMA16(a, b, c) __builtin_amdgcn_mfma_f32_16x16x32_bf16((a), (b), (c), 0, 0, 0)

// ---------------------------------------------------------------------------
// fp32 -> bf16 bulk convert (for Wq, Wk)
// ---------------------------------------------------------------------------
__global__ __launch_bounds__(256) void cvt_f32_bf16(const float* __restrict__ src,
                                                    short* __restrict__ dst, int n) {
  int i = (blockIdx.x * 256 + threadIdx.x) * 8;
  if (i + 7 < n) {
    f32x4 a = *(const f32x4*)(src + i);
    f32x4 b = *(const f32x4*)(src + i + 4);
    s16x8 o;
    o[0] = f2bf(a[0]); o[1] = f2bf(a[1]); o[2] = f2bf(a[2]); o[3] = f2bf(a[3]);
    o[4] = f2bf(b[0]); o[5] = f2bf(b[1]); o[6] = f2bf(b[2]); o[7] = f2bf(b[3]);
    *(s16x8*)(dst + i) = o;
  }
}

// ---------------------------------------------------------------------------
// Projection: out[m,h] = bf16( sum_k X[m,k]*W[h,k] + bias[h] )
// X: (M x 1024) fp32, Wb: (512 x 1024) bf16, out: (M x 512) bf16
// Block: 32 rows x 512 cols, 256 threads (4 waves, wave tile 32x128).
// ---------------------------------------------------------------------------
__global__ __launch_bounds__(256) void proj_kernel(const float* __restrict__ X,
                                                   const short* __restrict__ Wb,
                                                   const float* __restrict__ bias,
                                                   short* __restrict__ out) {
  const int m0 = blockIdx.x * 32;
  const int tid = threadIdx.x;
  const int lane = tid & 63;
  const int wid = tid >> 6;  // wave = column block of 128

  __shared__ short At[32 * 64];    // 4 KB, row stride 128 B, XOR-swizzled
  __shared__ short Bt[512 * 64];   // 64 KB, row stride 128 B, XOR-swizzled

  f32x4 acc[2][8] = {};

  const int ar = tid >> 3;          // 0..31 (A staging row)
  const int agk = (tid & 7) * 8;    // 0..56 (A staging k-group)

  for (int kt = 0; kt < 16; ++kt) {
    __syncthreads();
    // ---- stage A (fp32 -> bf16 via registers) ----
    {
      const float* sp = X + (long)(m0 + ar) * ND + kt * 64 + agk;
      f32x4 a = *(const f32x4*)sp;
      f32x4 b = *(const f32x4*)(sp + 4);
      s16x8 o;
      o[0] = f2bf(a[0]); o[1] = f2bf(a[1]); o[2] = f2bf(a[2]); o[3] = f2bf(a[3]);
      o[4] = f2bf(b[0]); o[5] = f2bf(b[1]); o[6] = f2bf(b[2]); o[7] = f2bf(b[3]);
      int off = (ar * 128 + agk * 2) ^ ((ar & 7) << 4);
      *(s16x8*)((char*)At + off) = o;
    }
    // ---- stage B via global_load_lds with pre-swizzled source ----
    {
      const char* wb = (const char*)Wb;
      for (int i = 0; i < 16; ++i) {
        int p = (i * 256 + tid) * 16;   // linear LDS byte
        int row = p >> 7;
        long gsrc = (long)row * 2048 + kt * 128 + ((p & 127) ^ ((row & 7) << 4));
        gl_lds16(wb + gsrc, (char*)Bt + i * 4096 + wid * 1024);
      }
    }
    asm volatile("s_waitcnt vmcnt(0)" ::: "memory");
    __syncthreads();
    // ---- compute ----
#pragma unroll
    for (int kk = 0; kk < 2; ++kk) {
      const int kofs = (kk * 32 + (lane >> 4) * 8) * 2;
      s16x8 af[2], bfr[8];
#pragma unroll
      for (int i = 0; i < 2; ++i) {
        int r = i * 16 + (lane & 15);
        int off = (r * 128 + kofs) ^ ((r & 7) << 4);
        af[i] = *(const s16x8*)((const char*)At + off);
      }
#pragma unroll
      for (int j = 0; j < 8; ++j) {
        int r = wid * 128 + j * 16 + (lane & 15);
        int off = (r * 128 + kofs) ^ ((r & 7) << 4);
        bfr[j] = *(const s16x8*)((const char*)Bt + off);
      }
#pragma unroll
      for (int i = 0; i < 2; ++i)
#pragma unroll
        for (int j = 0; j < 8; ++j) acc[i][j] = MFMA16(af[i], bfr[j], acc[i][j]);
    }
  }
  // ---- epilogue: bias add, bf16 store ----
#pragma unroll
  for (int j = 0; j < 8; ++j) {
    int col = wid * 128 + j * 16 + (lane & 15);
    float bv = bias[col];
#pragma unroll
    for (int i = 0; i < 2; ++i) {
      int rbase = m0 + i * 16 + ((lane >> 4) & 3) * 4;
#pragma unroll
      for (int r = 0; r < 4; ++r) {
        out[(long)(rbase + r) * NH + col] = f2bf(acc[i][j][r] + bv);
      }
    }
  }
}

// ---------------------------------------------------------------------------
// Phase A: rl[b,s] = 1 / sum_t exp(q[b,s,:].k[b,t,:] * SCALE)
// Block: (sblk, b), 64 s-rows, 4 waves x 16 rows. Q frags hoisted in regs.
// ---------------------------------------------------------------------------
__global__ __launch_bounds__(256) void attn_rowsum(const short* __restrict__ qb,
                                                   const short* __restrict__ kb,
                                                   float* __restrict__ rl) {
  const int b = blockIdx.y, sblk = blockIdx.x;
  const int tid = threadIdx.x, lane = tid & 63, wid = tid >> 6;
  const int srow = sblk * 64 + wid * 16;

  __shared__ short Kt[64 * 512];  // 64 KB, row stride 1024 B, XOR-swizzled

  s16x8 qf[16];
  {
    const short* qp = qb + (long)(b * NS + srow + (lane & 15)) * NH + (lane >> 4) * 8;
#pragma unroll
    for (int kk = 0; kk < 16; ++kk) qf[kk] = *(const s16x8*)(qp + kk * 32);
  }

  float part[4] = {0.f, 0.f, 0.f, 0.f};
  const char* kbase = (const char*)(kb + (long)b * NS * NH);

  for (int tt = 0; tt < 32; ++tt) {
    __syncthreads();
    const char* tb = kbase + (long)tt * 64 * 1024;
    for (int i = 0; i < 16; ++i) {
      int p = (i * 256 + tid) * 16;
      int src = p ^ (((p >> 10) & 7) << 4);
      gl_lds16(tb + src, (char*)Kt + i * 4096 + wid * 1024);
    }
    asm volatile("s_waitcnt vmcnt(0)" ::: "memory");
    __syncthreads();

    f32x4 acc[4] = {};
#pragma unroll
    for (int kk = 0; kk < 16; ++kk) {
      const int kofs = (kk * 32 + (lane >> 4) * 8) * 2;
#pragma unroll
      for (int cf = 0; cf < 4; ++cf) {
        int t = cf * 16 + (lane & 15);
        int off = (t * 1024 + kofs) ^ ((t & 7) << 4);
        s16x8 bfr = *(const s16x8*)((const char*)Kt + off);
        acc[cf] = MFMA16(qf[kk], bfr, acc[cf]);
      }
    }
#pragma unroll
    for (int cf = 0; cf < 4; ++cf)
#pragma unroll
      for (int r = 0; r < 4; ++r) part[r] += __expf(acc[cf][r] * SCALE);
  }

#pragma unroll
  for (int m = 1; m < 16; m <<= 1)
#pragma unroll
    for (int r = 0; r < 4; ++r) part[r] += __shfl_xor(part[r], m, 64);

  if ((lane & 15) == 0) {
    int g = lane >> 4;
#pragma unroll
    for (int r = 0; r < 4; ++r)
      rl[b * NS + srow + g * 4 + r] = 1.0f / part[r];
  }
}

// ---------------------------------------------------------------------------
// Phase B: w[b,t] = sum_s exp(q[b,s,:].k[b,t,:] * SCALE) * rl[b,s]
// Symmetric: K frags hoisted, Q streamed through LDS.
// ---------------------------------------------------------------------------
__global__ __launch_bounds__(256) void attn_colsum(const short* __restrict__ qb,
                                                   const short* __restrict__ kb,
                                                   const float* __restrict__ rl,
                                                   float* __restrict__ w) {
  const int b = blockIdx.y, tblk = blockIdx.x;
  const int tid = threadIdx.x, lane = tid & 63, wid = tid >> 6;
  const int trow = tblk * 64 + wid * 16;

  __shared__ short Qt[64 * 512];  // 64 KB

  s16x8 kf[16];
  {
    const short* kp = kb + (long)(b * NS + trow + (lane & 15)) * NH + (lane >> 4) * 8;
#pragma unroll
    for (int kk = 0; kk < 16; ++kk) kf[kk] = *(const s16x8*)(kp + kk * 32);
  }

  float part[4] = {0.f, 0.f, 0.f, 0.f};
  const char* qbase = (const char*)(qb + (long)b * NS * NH);
  const float* rlb = rl + b * NS;

  for (int ss = 0; ss < 32; ++ss) {
    __syncthreads();
    const char* sb = qbase + (long)ss * 64 * 1024;
    for (int i = 0; i < 16; ++i) {
      int p = (i * 256 + tid) * 16;
      int src = p ^ (((p >> 10) & 7) << 4);
      gl_lds16(sb + src, (char*)Qt + i * 4096 + wid * 1024);
    }
    asm volatile("s_waitcnt vmcnt(0)" ::: "memory");
    __syncthreads();

    f32x4 acc[4] = {};
#pragma unroll
    for (int kk = 0; kk < 16; ++kk) {
      const int kofs = (kk * 32 + (lane >> 4) * 8) * 2;
#pragma unroll
      for (int cf = 0; cf < 4; ++cf) {
        int s = cf * 16 + (lane & 15);
        int off = (s * 1024 + kofs) ^ ((s & 7) << 4);
        s16x8 bfr = *(const s16x8*)((const char*)Qt + off);
        acc[cf] = MFMA16(kf[kk], bfr, acc[cf]);
      }
    }
#pragma unroll
    for (int cf = 0; cf < 4; ++cf) {
      float rv = rlb[ss * 64 + cf * 16 + (lane & 15)];
#pragma unroll
      for (int r = 0; r < 4; ++r) part[r] += __expf(acc[cf][r] * SCALE) * rv;
    }
  }

#pragma unroll
  for (int m = 1; m < 16; m <<= 1)
#pragma unroll
    for (int r = 0; r < 4; ++r) part[r] += __shfl_xor(part[r], m, 64);

  if ((lane & 15) == 0) {
    int g = lane >> 4;
#pragma unroll
    for (int r = 0; r < 4; ++r)
      w[b * NS + trow + g * 4 + r] = part[r];
  }
}

// ---------------------------------------------------------------------------
// mf1[b,d] = mean_s f1[b,s,d]     (fp32-exact)
// grid (4 dchunk, 16 schunk, 16 b), 256 threads
// ---------------------------------------------------------------------------
__global__ __launch_bounds__(256) void colmean(const float* __restrict__ f1,
                                               float* __restrict__ mf1) {
  int d = blockIdx.x * 256 + threadIdx.x;
  int b = blockIdx.z;
  long base = ((long)b * NS + blockIdx.y * 128) * ND + d;
  float acc = 0.f;
  for (int s = 0; s < 128; ++s) acc += f1[base + (long)s * ND];
  atomicAdd(&mf1[b * ND + d], acc * (1.0f / 2048.0f));
}

// ---------------------------------------------------------------------------
// g[b,d] = sum_t w[b,t] * f2[b,t,d]    (fp32-exact given w)
// ---------------------------------------------------------------------------
__global__ __launch_bounds__(256) void weighted_colsum(const float* __restrict__ f2,
                                                       const float* __restrict__ w,
                                                       float* __restrict__ g) {
  int d = blockIdx.x * 256 + threadIdx.x;
  int b = blockIdx.z;
  int t0 = blockIdx.y * 128;
  long base = ((long)b * NS + t0) * ND + d;
  const float* wr = w + b * NS + t0;
  float acc = 0.f;
  for (int t = 0; t < 128; ++t) acc += wr[t] * f2[base + (long)t * ND];
  atomicAdd(&g[b * ND + d], acc);
}

// ---------------------------------------------------------------------------
// Final: meanq = mf1@Wq^T + bq ; att = (g@Wv^T)/2048 + bv ; pooled = [meanq,att]
// h = relu(pooled@Wc1^T + bc1) ; out[b] = h.Wc2 + bc2
// grid 16 blocks (one per b), 512 threads (one per h index)
// ---------------------------------------------------------------------------
__global__ __launch_bounds__(512) void final_mlp(
    const float* __restrict__ mf1, const float* __restrict__ g,
    const float* __restrict__ Wq, const float* __restrict__ bq,
    const float* __restrict__ Wv, const float* __restrict__ bv,
    const float* __restrict__ Wc1, const float* __restrict__ bc1,
    const float* __restrict__ Wc2, const float* __restrict__ bc2,
    float* __restrict__ out) {
  const int b = blockIdx.x;
  const int j = threadIdx.x;  // 0..511
  __shared__ float pooled[1024];
  __shared__ float red[8];

  const f32x4* m4 = (const f32x4*)(mf1 + b * ND);
  const f32x4* g4 = (const f32x4*)(g + b * ND);
  const f32x4* wq4 = (const f32x4*)(Wq + (long)j * ND);
  const f32x4* wv4 = (const f32x4*)(Wv + (long)j * ND);
  float mq = 0.f, av = 0.f;
  for (int i = 0; i < 256; ++i) {
    f32x4 a = m4[i], x = wq4[i];
    mq += a[0] * x[0] + a[1] * x[1] + a[2] * x[2] + a[3] * x[3];
    f32x4 c = g4[i], y = wv4[i];
    av += c[0] * y[0] + c[1] * y[1] + c[2] * y[2] + c[3] * y[3];
  }
  pooled[j] = mq + bq[j];
  pooled[512 + j] = av * (1.0f / 2048.0f) + bv[j];
  __syncthreads();

  const f32x4* p4 = (const f32x4*)pooled;
  const f32x4* wc4 = (const f32x4*)(Wc1 + (long)j * ND);
  float h = bc1[j];
  for (int i = 0; i < 256; ++i) {
    f32x4 p = p4[i], y = wc4[i];
    h += p[0] * y[0] + p[1] * y[1] + p[2] * y[2] + p[3] * y[3];
  }
  h = fmaxf(h, 0.f) * Wc2[j];

#pragma unroll
  for (int m = 1; m < 64; m <<= 1) h += __shfl_xor(h, m, 64);
  if ((j & 63) == 0) red[j >> 6] = h;
  __syncthreads();
  if (j == 0) {
    float t = 0.f;
#pragma unroll
    for (int k = 0; k < 8; ++k) t += red[k];
    out[b] = t + bc2[0];
  }
}

// ---------------------------------------------------------------------------
extern "C" void kernel_launch(void* const* d_in, const int* in_sizes, int n_in,
                              void* d_out, int out_size, void* d_ws, size_t ws_size,
                              hipStream_t stream) {
  const float* f1 = (const float*)d_in[0];
  const float* f2 = (const float*)d_in[1];
  const float* Wq = (const float*)d_in[2];
  const float* bq = (const float*)d_in[3];
  const float* Wk = (const float*)d_in[4];
  const float* bk = (const float*)d_in[5];
  const float* Wv = (const float*)d_in[6];
  const float* bv = (const float*)d_in[7];
  const float* Wc1 = (const float*)d_in[8];
  const float* bc1 = (const float*)d_in[9];
  const float* Wc2 = (const float*)d_in[10];
  const float* bc2 = (const float*)d_in[11];
  float* out = (float*)d_out;

  char* ws = (char*)d_ws;
  short* qbuf = (short*)ws;                          // 32 MB  (B*S*H bf16)
  short* kbuf = (short*)(ws + (32l << 20));          // 32 MB
  short* Wqb = (short*)(ws + (64l << 20));           // 1 MB
  short* Wkb = (short*)(ws + (65l << 20));           // 1 MB
  float* rl = (float*)(ws + (66l << 20));            // 128 KB
  float* wbuf = (float*)(ws + (66l << 20) + (128l << 10));  // 128 KB
  float* mf1 = (float*)(ws + (66l << 20) + (256l << 10));   // 64 KB
  float* gbuf = (float*)(ws + (66l << 20) + (320l << 10));  // 64 KB

  hipMemsetAsync(mf1, 0, NB * ND * sizeof(float), stream);
  hipMemsetAsync(gbuf, 0, NB * ND * sizeof(float), stream);

  cvt_f32_bf16<<<256, 256, 0, stream>>>(Wq, Wqb, NH * ND);
  cvt_f32_bf16<<<256, 256, 0, stream>>>(Wk, Wkb, NH * ND);

  proj_kernel<<<NB * NS / 32, 256, 0, stream>>>(f1, Wqb, bq, qbuf);
  proj_kernel<<<NB * NS / 32, 256, 0, stream>>>(f2, Wkb, bk, kbuf);

  attn_rowsum<<<dim3(NS / 64, NB), 256, 0, stream>>>(qbuf, kbuf, rl);
  attn_colsum<<<dim3(NS / 64, NB), 256, 0, stream>>>(qbuf, kbuf, rl, wbuf);

  colmean<<<dim3(4, 16, 16), 256, 0, stream>>>(f1, mf1);
  weighted_colsum<<<dim3(4, 16, 16), 256, 0, stream>>>(f2, wbuf, gbuf);

  final_mlp<<<NB, 512, 0, stream>>>(mf1, gbuf, Wq, bq, Wv, bv, Wc1, bc1, Wc2,
                                    bc2, out);
}

// Round 5
// 733.372 us; speedup vs baseline: 1.0987x; 1.0987x over previous
//
#include <hip/hip_runtime.h>
#include <stdint.h>

#define NB   16
#define NS   2048
#define ND   1024
#define NH   512
#define SCALE 0.044194173824159216f  // 1/sqrt(512)

typedef __attribute__((ext_vector_type(4))) float f32x4;
typedef __attribute__((ext_vector_type(8))) short s16x8;
typedef __attribute__((ext_vector_type(4))) short s16x4;

__device__ __forceinline__ short f2bf(float f) {
  __bf16 h = (__bf16)f;
  return __builtin_bit_cast(short, h);
}
__device__ __forceinline__ float bf2f(short s) {
  unsigned int u = ((unsigned int)(unsigned short)s) << 16;
  return __builtin_bit_cast(float, u);
}

__device__ __forceinline__ void gl_lds16(const void* g, void* l) {
  __builtin_amdgcn_global_load_lds(
      (const __attribute__((address_space(1))) void*)g,
      (__attribute__((address_space(3))) void*)l, 16, 0, 0);
}

#define MFMA16(a, b, c) __builtin_amdgcn_mfma_f32_16x16x32_bf16((a), (b), (c), 0, 0, 0)

// ---------------------------------------------------------------------------
// fp32 -> bf16 bulk convert (for Wq, Wk)
// ---------------------------------------------------------------------------
__global__ __launch_bounds__(256) void cvt_f32_bf16(const float* __restrict__ src,
                                                    short* __restrict__ dst, int n) {
  int i = (blockIdx.x * 256 + threadIdx.x) * 8;
  if (i + 7 < n) {
    f32x4 a = *(const f32x4*)(src + i);
    f32x4 b = *(const f32x4*)(src + i + 4);
    s16x8 o;
    o[0] = f2bf(a[0]); o[1] = f2bf(a[1]); o[2] = f2bf(a[2]); o[3] = f2bf(a[3]);
    o[4] = f2bf(b[0]); o[5] = f2bf(b[1]); o[6] = f2bf(b[2]); o[7] = f2bf(b[3]);
    *(s16x8*)(dst + i) = o;
  }
}

// ---------------------------------------------------------------------------
// Projection: out[m,h] = bf16( sum_k X[m,k]*W[h,k] + bias[h] )
// ---------------------------------------------------------------------------
__global__ __launch_bounds__(256) void proj_kernel(const float* __restrict__ X,
                                                   const short* __restrict__ Wb,
                                                   const float* __restrict__ bias,
                                                   short* __restrict__ out) {
  const int m0 = blockIdx.x * 32;
  const int tid = threadIdx.x;
  const int lane = tid & 63;
  const int wid = tid >> 6;

  __shared__ short At[32 * 64];
  __shared__ short Bt[512 * 64];

  f32x4 acc[2][8] = {};

  const int ar = tid >> 3;
  const int agk = (tid & 7) * 8;

  for (int kt = 0; kt < 16; ++kt) {
    __syncthreads();
    {
      const float* sp = X + (long)(m0 + ar) * ND + kt * 64 + agk;
      f32x4 a = *(const f32x4*)sp;
      f32x4 b = *(const f32x4*)(sp + 4);
      s16x8 o;
      o[0] = f2bf(a[0]); o[1] = f2bf(a[1]); o[2] = f2bf(a[2]); o[3] = f2bf(a[3]);
      o[4] = f2bf(b[0]); o[5] = f2bf(b[1]); o[6] = f2bf(b[2]); o[7] = f2bf(b[3]);
      int off = (ar * 128 + agk * 2) ^ ((ar & 7) << 4);
      *(s16x8*)((char*)At + off) = o;
    }
    {
      const char* wb = (const char*)Wb;
      for (int i = 0; i < 16; ++i) {
        int p = (i * 256 + tid) * 16;
        int row = p >> 7;
        long gsrc = (long)row * 2048 + kt * 128 + ((p & 127) ^ ((row & 7) << 4));
        gl_lds16(wb + gsrc, (char*)Bt + i * 4096 + wid * 1024);
      }
    }
    asm volatile("s_waitcnt vmcnt(0)" ::: "memory");
    __syncthreads();
#pragma unroll
    for (int kk = 0; kk < 2; ++kk) {
      const int kofs = (kk * 32 + (lane >> 4) * 8) * 2;
      s16x8 af[2], bfr[8];
#pragma unroll
      for (int i = 0; i < 2; ++i) {
        int r = i * 16 + (lane & 15);
        int off = (r * 128 + kofs) ^ ((r & 7) << 4);
        af[i] = *(const s16x8*)((const char*)At + off);
      }
#pragma unroll
      for (int j = 0; j < 8; ++j) {
        int r = wid * 128 + j * 16 + (lane & 15);
        int off = (r * 128 + kofs) ^ ((r & 7) << 4);
        bfr[j] = *(const s16x8*)((const char*)Bt + off);
      }
#pragma unroll
      for (int i = 0; i < 2; ++i)
#pragma unroll
        for (int j = 0; j < 8; ++j) acc[i][j] = MFMA16(af[i], bfr[j], acc[i][j]);
    }
  }
#pragma unroll
  for (int j = 0; j < 8; ++j) {
    int col = wid * 128 + j * 16 + (lane & 15);
    float bv = bias[col];
#pragma unroll
    for (int i = 0; i < 2; ++i) {
      int rbase = m0 + i * 16 + ((lane >> 4) & 3) * 4;
#pragma unroll
      for (int r = 0; r < 4; ++r) {
        out[(long)(rbase + r) * NH + col] = f2bf(acc[i][j][r] + bv);
      }
    }
  }
}

// ---------------------------------------------------------------------------
// P-path phase A: partial row sums of exp(QK^T*s) via atomics, store P^T bf16.
// Block: (sblk 16, thalf 2, b 16); 4 waves x 32 s-rows = 128 s rows/block.
// ---------------------------------------------------------------------------
__global__ __launch_bounds__(256) void attn_rowsum_p(const short* __restrict__ qb,
                                                     const short* __restrict__ kb,
                                                     float* __restrict__ rsum,
                                                     short* __restrict__ Pt) {
  const int sblk = blockIdx.x, thalf = blockIdx.y, b = blockIdx.z;
  const int tid = threadIdx.x, lane = tid & 63, wid = tid >> 6;
  const int s0 = sblk * 128 + wid * 32;

  __shared__ short Kt[64 * 512];  // 64 KB

  s16x8 qf[2][16];
#pragma unroll
  for (int i = 0; i < 2; ++i) {
    const short* qp = qb + (long)(b * NS + s0 + i * 16 + (lane & 15)) * NH + (lane >> 4) * 8;
#pragma unroll
    for (int kk = 0; kk < 16; ++kk) qf[i][kk] = *(const s16x8*)(qp + kk * 32);
  }

  float part[2][4] = {};
  const char* kbase = (const char*)(kb + (long)b * NS * NH) + (long)thalf * 1024 * 1024;

  for (int tt = 0; tt < 16; ++tt) {
    __syncthreads();
    const char* tb = kbase + (long)tt * 64 * 1024;
    for (int i = 0; i < 16; ++i) {
      int p = (i * 256 + tid) * 16;
      int src = p ^ (((p >> 10) & 7) << 4);
      gl_lds16(tb + src, (char*)Kt + i * 4096 + wid * 1024);
    }
    asm volatile("s_waitcnt vmcnt(0)" ::: "memory");
    __syncthreads();

    f32x4 acc[2][4] = {};
#pragma unroll
    for (int kk = 0; kk < 16; ++kk) {
      const int kofs = (kk * 32 + (lane >> 4) * 8) * 2;
      s16x8 bfr[4];
#pragma unroll
      for (int cf = 0; cf < 4; ++cf) {
        int t = cf * 16 + (lane & 15);
        int off = (t * 1024 + kofs) ^ ((t & 7) << 4);
        bfr[cf] = *(const s16x8*)((const char*)Kt + off);
      }
#pragma unroll
      for (int i = 0; i < 2; ++i)
#pragma unroll
        for (int cf = 0; cf < 4; ++cf) acc[i][cf] = MFMA16(qf[i][kk], bfr[cf], acc[i][cf]);
    }

#pragma unroll
    for (int i = 0; i < 2; ++i)
#pragma unroll
      for (int cf = 0; cf < 4; ++cf) {
        s16x4 pw;
        float e0 = __expf(acc[i][cf][0] * SCALE);
        float e1 = __expf(acc[i][cf][1] * SCALE);
        float e2 = __expf(acc[i][cf][2] * SCALE);
        float e3 = __expf(acc[i][cf][3] * SCALE);
        part[i][0] += e0; part[i][1] += e1; part[i][2] += e2; part[i][3] += e3;
        pw[0] = f2bf(e0); pw[1] = f2bf(e1); pw[2] = f2bf(e2); pw[3] = f2bf(e3);
        int t = thalf * 1024 + tt * 64 + cf * 16 + (lane & 15);
        long s_base = s0 + i * 16 + (lane >> 4) * 4;
        *(s16x4*)(Pt + (long)(b * NS + t) * NS + s_base) = pw;
      }
  }

#pragma unroll
  for (int m = 1; m < 16; m <<= 1)
#pragma unroll
    for (int i = 0; i < 2; ++i)
#pragma unroll
      for (int r = 0; r < 4; ++r) part[i][r] += __shfl_xor(part[i][r], m, 64);

  if ((lane & 15) == 0) {
#pragma unroll
    for (int i = 0; i < 2; ++i)
#pragma unroll
      for (int r = 0; r < 4; ++r)
        atomicAdd(&rsum[b * NS + s0 + i * 16 + (lane >> 4) * 4 + r], part[i][r]);
  }
}

__global__ __launch_bounds__(256) void recip_kernel(const float* __restrict__ rsum,
                                                    float* __restrict__ rl) {
  int i = blockIdx.x * 256 + threadIdx.x;
  if (i < NB * NS) rl[i] = 1.0f / rsum[i];
}

// ---------------------------------------------------------------------------
// P-path phase B: w[b,t] = sum_s P^T[b,t,s] * rl[b,s]   (memory-bound)
// ---------------------------------------------------------------------------
__global__ __launch_bounds__(256) void wsum_kernel(const short* __restrict__ Pt,
                                                   const float* __restrict__ rl,
                                                   float* __restrict__ w) {
  int gw = blockIdx.x * 4 + (threadIdx.x >> 6);
  int lane = threadIdx.x & 63;
  int b = gw >> 11, t = gw & 2047;
  const short* pr = Pt + (long)(b * NS + t) * NS + lane * 32;
  const float* rr = rl + b * NS + lane * 32;
  float acc = 0.f;
#pragma unroll
  for (int c = 0; c < 4; ++c) {
    s16x8 pv = *(const s16x8*)(pr + c * 8);
    f32x4 r0 = *(const f32x4*)(rr + c * 8);
    f32x4 r1 = *(const f32x4*)(rr + c * 8 + 4);
    acc += bf2f(pv[0]) * r0[0] + bf2f(pv[1]) * r0[1] + bf2f(pv[2]) * r0[2] +
           bf2f(pv[3]) * r0[3] + bf2f(pv[4]) * r1[0] + bf2f(pv[5]) * r1[1] +
           bf2f(pv[6]) * r1[2] + bf2f(pv[7]) * r1[3];
  }
#pragma unroll
  for (int m = 1; m < 64; m <<= 1) acc += __shfl_xor(acc, m, 64);
  if (lane == 0) w[b * NS + t] = acc;
}

// ---------------------------------------------------------------------------
// Fallback phase A (no P store): rl[b,s] = 1/sum_t exp(...)
// ---------------------------------------------------------------------------
__global__ __launch_bounds__(256) void attn_rowsum(const short* __restrict__ qb,
                                                   const short* __restrict__ kb,
                                                   float* __restrict__ rl) {
  const int b = blockIdx.y, sblk = blockIdx.x;
  const int tid = threadIdx.x, lane = tid & 63, wid = tid >> 6;
  const int srow = sblk * 64 + wid * 16;

  __shared__ short Kt[64 * 512];

  s16x8 qf[16];
  {
    const short* qp = qb + (long)(b * NS + srow + (lane & 15)) * NH + (lane >> 4) * 8;
#pragma unroll
    for (int kk = 0; kk < 16; ++kk) qf[kk] = *(const s16x8*)(qp + kk * 32);
  }

  float part[4] = {0.f, 0.f, 0.f, 0.f};
  const char* kbase = (const char*)(kb + (long)b * NS * NH);

  for (int tt = 0; tt < 32; ++tt) {
    __syncthreads();
    const char* tb = kbase + (long)tt * 64 * 1024;
    for (int i = 0; i < 16; ++i) {
      int p = (i * 256 + tid) * 16;
      int src = p ^ (((p >> 10) & 7) << 4);
      gl_lds16(tb + src, (char*)Kt + i * 4096 + wid * 1024);
    }
    asm volatile("s_waitcnt vmcnt(0)" ::: "memory");
    __syncthreads();

    f32x4 acc[4] = {};
#pragma unroll
    for (int kk = 0; kk < 16; ++kk) {
      const int kofs = (kk * 32 + (lane >> 4) * 8) * 2;
#pragma unroll
      for (int cf = 0; cf < 4; ++cf) {
        int t = cf * 16 + (lane & 15);
        int off = (t * 1024 + kofs) ^ ((t & 7) << 4);
        s16x8 bfr = *(const s16x8*)((const char*)Kt + off);
        acc[cf] = MFMA16(qf[kk], bfr, acc[cf]);
      }
    }
#pragma unroll
    for (int cf = 0; cf < 4; ++cf)
#pragma unroll
      for (int r = 0; r < 4; ++r) part[r] += __expf(acc[cf][r] * SCALE);
  }

#pragma unroll
  for (int m = 1; m < 16; m <<= 1)
#pragma unroll
    for (int r = 0; r < 4; ++r) part[r] += __shfl_xor(part[r], m, 64);

  if ((lane & 15) == 0) {
    int g = lane >> 4;
#pragma unroll
    for (int r = 0; r < 4; ++r)
      rl[b * NS + srow + g * 4 + r] = 1.0f / part[r];
  }
}

// ---------------------------------------------------------------------------
// Fallback phase B (recompute): w[b,t] = sum_s exp(...) * rl[b,s]
// ---------------------------------------------------------------------------
__global__ __launch_bounds__(256) void attn_colsum(const short* __restrict__ qb,
                                                   const short* __restrict__ kb,
                                                   const float* __restrict__ rl,
                                                   float* __restrict__ w) {
  const int b = blockIdx.y, tblk = blockIdx.x;
  const int tid = threadIdx.x, lane = tid & 63, wid = tid >> 6;
  const int trow = tblk * 64 + wid * 16;

  __shared__ short Qt[64 * 512];

  s16x8 kf[16];
  {
    const short* kp = kb + (long)(b * NS + trow + (lane & 15)) * NH + (lane >> 4) * 8;
#pragma unroll
    for (int kk = 0; kk < 16; ++kk) kf[kk] = *(const s16x8*)(kp + kk * 32);
  }

  float part[4] = {0.f, 0.f, 0.f, 0.f};
  const char* qbase = (const char*)(qb + (long)b * NS * NH);
  const float* rlb = rl + b * NS;

  for (int ss = 0; ss < 32; ++ss) {
    __syncthreads();
    const char* sb = qbase + (long)ss * 64 * 1024;
    for (int i = 0; i < 16; ++i) {
      int p = (i * 256 + tid) * 16;
      int src = p ^ (((p >> 10) & 7) << 4);
      gl_lds16(sb + src, (char*)Qt + i * 4096 + wid * 1024);
    }
    asm volatile("s_waitcnt vmcnt(0)" ::: "memory");
    __syncthreads();

    f32x4 acc[4] = {};
#pragma unroll
    for (int kk = 0; kk < 16; ++kk) {
      const int kofs = (kk * 32 + (lane >> 4) * 8) * 2;
#pragma unroll
      for (int cf = 0; cf < 4; ++cf) {
        int s = cf * 16 + (lane & 15);
        int off = (s * 1024 + kofs) ^ ((s & 7) << 4);
        s16x8 bfr = *(const s16x8*)((const char*)Qt + off);
        acc[cf] = MFMA16(kf[kk], bfr, acc[cf]);
      }
    }
#pragma unroll
    for (int cf = 0; cf < 4; ++cf) {
      float rv = rlb[ss * 64 + cf * 16 + (lane & 15)];
#pragma unroll
      for (int r = 0; r < 4; ++r) part[r] += __expf(acc[cf][r] * SCALE) * rv;
    }
  }

#pragma unroll
  for (int m = 1; m < 16; m <<= 1)
#pragma unroll
    for (int r = 0; r < 4; ++r) part[r] += __shfl_xor(part[r], m, 64);

  if ((lane & 15) == 0) {
    int g = lane >> 4;
#pragma unroll
    for (int r = 0; r < 4; ++r)
      w[b * NS + trow + g * 4 + r] = part[r];
  }
}

// ---------------------------------------------------------------------------
// mf1[b,d] = mean_s f1[b,s,d]
// ---------------------------------------------------------------------------
__global__ __launch_bounds__(256) void colmean(const float* __restrict__ f1,
                                               float* __restrict__ mf1) {
  int d = blockIdx.x * 256 + threadIdx.x;
  int b = blockIdx.z;
  long base = ((long)b * NS + blockIdx.y * 128) * ND + d;
  float acc = 0.f;
  for (int s = 0; s < 128; ++s) acc += f1[base + (long)s * ND];
  atomicAdd(&mf1[b * ND + d], acc * (1.0f / 2048.0f));
}

// ---------------------------------------------------------------------------
// g[b,d] = sum_t w[b,t] * f2[b,t,d]
// ---------------------------------------------------------------------------
__global__ __launch_bounds__(256) void weighted_colsum(const float* __restrict__ f2,
                                                       const float* __restrict__ w,
                                                       float* __restrict__ g) {
  int d = blockIdx.x * 256 + threadIdx.x;
  int b = blockIdx.z;
  int t0 = blockIdx.y * 128;
  long base = ((long)b * NS + t0) * ND + d;
  const float* wr = w + b * NS + t0;
  float acc = 0.f;
  for (int t = 0; t < 128; ++t) acc += wr[t] * f2[base + (long)t * ND];
  atomicAdd(&g[b * ND + d], acc);
}

// ---------------------------------------------------------------------------
// pooled[b,j]      = dot(mf1[b,:], Wq[j,:]) + bq[j]            (j<512)
// pooled[b,512+j]  = dot(g[b,:],  Wv[j,:])/2048 + bv[j]
// ---------------------------------------------------------------------------
__global__ __launch_bounds__(256) void pooled_kernel(
    const float* __restrict__ mf1, const float* __restrict__ g,
    const float* __restrict__ Wq, const float* __restrict__ bq,
    const float* __restrict__ Wv, const float* __restrict__ bv,
    float* __restrict__ pooled) {
  int gw = blockIdx.x * 4 + (threadIdx.x >> 6);  // 0..1023
  int lane = threadIdx.x & 63;
  const float* wrow;
  const float* xbase;
  float bias, scale;
  if (gw < 512) {
    wrow = Wq + (long)gw * ND; xbase = mf1; bias = bq[gw]; scale = 1.0f;
  } else {
    wrow = Wv + (long)(gw - 512) * ND; xbase = g; bias = bv[gw - 512];
    scale = 1.0f / 2048.0f;
  }
  f32x4 wreg[4];
#pragma unroll
  for (int i = 0; i < 4; ++i) wreg[i] = *(const f32x4*)(wrow + i * 256 + lane * 4);
  for (int b = 0; b < NB; ++b) {
    const f32x4* x = (const f32x4*)(xbase + (long)b * ND);
    float p = 0.f;
#pragma unroll
    for (int i = 0; i < 4; ++i) {
      f32x4 xv = x[i * 64 + lane];
      p += wreg[i][0] * xv[0] + wreg[i][1] * xv[1] + wreg[i][2] * xv[2] + wreg[i][3] * xv[3];
    }
#pragma unroll
    for (int m = 1; m < 64; m <<= 1) p += __shfl_xor(p, m, 64);
    if (lane == 0) pooled[b * ND + gw] = p * scale + bias;
  }
}

// ---------------------------------------------------------------------------
// out[b] = bc2 + sum_j relu(dot(pooled[b,:], Wc1[j,:]) + bc1[j]) * Wc2[j]
// ---------------------------------------------------------------------------
__global__ __launch_bounds__(256) void out_kernel(
    const float* __restrict__ pooled, const float* __restrict__ Wc1,
    const float* __restrict__ bc1, const float* __restrict__ Wc2,
    const float* __restrict__ bc2, float* __restrict__ out) {
  int j = blockIdx.x * 4 + (threadIdx.x >> 6);  // 0..511
  int lane = threadIdx.x & 63;
  f32x4 wreg[4];
#pragma unroll
  for (int i = 0; i < 4; ++i)
    wreg[i] = *(const f32x4*)(Wc1 + (long)j * ND + i * 256 + lane * 4);
  for (int b = 0; b < NB; ++b) {
    const f32x4* x = (const f32x4*)(pooled + (long)b * ND);
    float p = 0.f;
#pragma unroll
    for (int i = 0; i < 4; ++i) {
      f32x4 xv = x[i * 64 + lane];
      p += wreg[i][0] * xv[0] + wreg[i][1] * xv[1] + wreg[i][2] * xv[2] + wreg[i][3] * xv[3];
    }
#pragma unroll
    for (int m = 1; m < 64; m <<= 1) p += __shfl_xor(p, m, 64);
    if (lane == 0) {
      float h = fmaxf(p + bc1[j], 0.f) * Wc2[j];
      if (j == 0) h += bc2[0];
      atomicAdd(&out[b], h);
    }
  }
}

// ---------------------------------------------------------------------------
extern "C" void kernel_launch(void* const* d_in, const int* in_sizes, int n_in,
                              void* d_out, int out_size, void* d_ws, size_t ws_size,
                              hipStream_t stream) {
  const float* f1 = (const float*)d_in[0];
  const float* f2 = (const float*)d_in[1];
  const float* Wq = (const float*)d_in[2];
  const float* bq = (const float*)d_in[3];
  const float* Wk = (const float*)d_in[4];
  const float* bk = (const float*)d_in[5];
  const float* Wv = (const float*)d_in[6];
  const float* bv = (const float*)d_in[7];
  const float* Wc1 = (const float*)d_in[8];
  const float* bc1 = (const float*)d_in[9];
  const float* Wc2 = (const float*)d_in[10];
  const float* bc2 = (const float*)d_in[11];
  float* out = (float*)d_out;

  char* ws = (char*)d_ws;
  short* qbuf = (short*)ws;                                   // 32 MiB
  short* kbuf = (short*)(ws + (32l << 20));                   // 32 MiB
  short* Wqb = (short*)(ws + (64l << 20));                    // 1 MiB
  short* Wkb = (short*)(ws + (65l << 20));                    // 1 MiB
  float* rsum = (float*)(ws + (66l << 20));                   // 128 KB
  float* rl = (float*)(ws + (66l << 20) + (128l << 10));      // 128 KB
  float* wbuf = (float*)(ws + (66l << 20) + (256l << 10));    // 128 KB
  float* mf1 = (float*)(ws + (66l << 20) + (384l << 10));     // 64 KB
  float* gbuf = (float*)(ws + (66l << 20) + (448l << 10));    // 64 KB
  float* pooled = (float*)(ws + (66l << 20) + (512l << 10));  // 64 KB
  short* Pt = (short*)(ws + (68l << 20));                     // 128 MiB (B*S*S bf16)

  const bool useP = ws_size >= ((68l << 20) + (long)NB * NS * NS * 2);

  hipMemsetAsync(mf1, 0, NB * ND * sizeof(float), stream);
  hipMemsetAsync(gbuf, 0, NB * ND * sizeof(float), stream);
  hipMemsetAsync(out, 0, NB * sizeof(float), stream);
  if (useP) hipMemsetAsync(rsum, 0, NB * NS * sizeof(float), stream);

  cvt_f32_bf16<<<256, 256, 0, stream>>>(Wq, Wqb, NH * ND);
  cvt_f32_bf16<<<256, 256, 0, stream>>>(Wk, Wkb, NH * ND);

  proj_kernel<<<NB * NS / 32, 256, 0, stream>>>(f1, Wqb, bq, qbuf);
  proj_kernel<<<NB * NS / 32, 256, 0, stream>>>(f2, Wkb, bk, kbuf);

  if (useP) {
    attn_rowsum_p<<<dim3(16, 2, NB), 256, 0, stream>>>(qbuf, kbuf, rsum, Pt);
    recip_kernel<<<NB * NS / 256, 256, 0, stream>>>(rsum, rl);
    wsum_kernel<<<NB * NS / 4, 256, 0, stream>>>(Pt, rl, wbuf);
  } else {
    attn_rowsum<<<dim3(NS / 64, NB), 256, 0, stream>>>(qbuf, kbuf, rl);
    attn_colsum<<<dim3(NS / 64, NB), 256, 0, stream>>>(qbuf, kbuf, rl, wbuf);
  }

  colmean<<<dim3(4, 16, 16), 256, 0, stream>>>(f1, mf1);
  weighted_colsum<<<dim3(4, 16, 16), 256, 0, stream>>>(f2, wbuf, gbuf);

  pooled_kernel<<<256, 256, 0, stream>>>(mf1, gbuf, Wq, bq, Wv, bv, pooled);
  out_kernel<<<128, 256, 0, stream>>>(pooled, Wc1, bc1, Wc2, bc2, out);
}